// Round 1
// baseline (255.233 us; speedup 1.0000x reference)
//
#include <hip/hip_runtime.h>
#include <stdint.h>

// MultiHeadSelfAttention: B=2, T=2048, C=1024, H=16, Dk=64, fp32 in/out.
// Strategy: cast to bf16, MFMA 16x16x32 GEMMs + flash attention, fp32 accum.

typedef __bf16 bf16;
typedef __bf16 bf16x8 __attribute__((ext_vector_type(8)));
typedef __bf16 bf16x4 __attribute__((ext_vector_type(4)));
typedef float  f32x4  __attribute__((ext_vector_type(4)));

#define SEQ_T 2048
#define CDIM 1024
#define BT   4096   // B*T

// async global->LDS, 16B per lane. LDS dest = wave-uniform base + lane*16.
__device__ __forceinline__ void gload16(const void* g, void* l) {
    __builtin_amdgcn_global_load_lds(
        (const __attribute__((address_space(1))) void*)(uintptr_t)g,
        (__attribute__((address_space(3))) void*)(uint32_t)(uintptr_t)l,
        16, 0, 0);
}

// ---------------------------------------------------------------- convert
__global__ __launch_bounds__(256) void k_convert(
    const float* __restrict__ x, const float* __restrict__ wqkv,
    const float* __restrict__ wout,
    bf16* __restrict__ xb, bf16* __restrict__ wqb, bf16* __restrict__ wob) {
    const int NX = (BT * CDIM) / 4;        // 1048576
    const int NQ = (3 * CDIM * CDIM) / 4;  // 786432
    const int NO = (CDIM * CDIM) / 4;      // 262144
    int i = blockIdx.x * 256 + threadIdx.x;
    const float4* src; bf16* dst; int j;
    if (i < NX)                    { src = (const float4*)x;    dst = xb;  j = i; }
    else if ((j = i - NX) < NQ)    { src = (const float4*)wqkv; dst = wqb; }
    else if ((j = i - NX - NQ) < NO) { src = (const float4*)wout; dst = wob; }
    else return;
    float4 v = src[j];
    bf16x4 o = { (bf16)v.x, (bf16)v.y, (bf16)v.z, (bf16)v.w };
    ((bf16x4*)dst)[j] = o;
}

// ------------------------------------------------------------- GEMM core
// C[128x128] = A[m0..][K=1024] * Bw[n0..][K=1024]^T, both K-contiguous (bf16).
// 4 waves, each 64x64 (4x4 MFMA tiles). LDS chunk index XOR-swizzled with
// ((row>>1)&3) so ds_read_b128 lands at 2-way bank aliasing (free, m136).
__device__ __forceinline__ void gemm_core(
    const bf16* __restrict__ A, const bf16* __restrict__ Bw,
    bf16* As, bf16* Bs, int m0, int n0, int tid, f32x4 (&acc)[4][4]) {
    const int lane = tid & 63, wv = tid >> 6;
    const int quad = lane >> 4, lo = lane & 15;
    const int wm = (wv >> 1) * 64, wn = (wv & 1) * 64;
#pragma unroll
    for (int mi = 0; mi < 4; ++mi)
#pragma unroll
        for (int ni = 0; ni < 4; ++ni) acc[mi][ni] = 0.0f;

    for (int kk = 0; kk < 1024; kk += 32) {
        __syncthreads();
#pragma unroll
        for (int c = 0; c < 2; ++c) {
            int slot = c * 256 + tid;
            int row = slot >> 2, sc = slot & 3;
            int g = sc ^ ((row >> 1) & 3);                 // source-chunk swizzle
            bf16* ldsA = As + c * 2048 + (tid & 192) * 8;  // wave-uniform base
            bf16* ldsB = Bs + c * 2048 + (tid & 192) * 8;
            gload16(A  + (m0 + row) * 1024 + kk + g * 8, ldsA);
            gload16(Bw + (n0 + row) * 1024 + kk + g * 8, ldsB);
        }
        __syncthreads();
        bf16x8 af[4], bb[4];
#pragma unroll
        for (int mi = 0; mi < 4; ++mi) {
            int row = wm + mi * 16 + lo;
            int ch = quad ^ ((row >> 1) & 3);
            af[mi] = *(const bf16x8*)(As + row * 32 + ch * 8);
        }
#pragma unroll
        for (int ni = 0; ni < 4; ++ni) {
            int row = wn + ni * 16 + lo;
            int ch = quad ^ ((row >> 1) & 3);
            bb[ni] = *(const bf16x8*)(Bs + row * 32 + ch * 8);
        }
#pragma unroll
        for (int mi = 0; mi < 4; ++mi)
#pragma unroll
            for (int ni = 0; ni < 4; ++ni)
                acc[mi][ni] = __builtin_amdgcn_mfma_f32_16x16x32_bf16(
                    af[mi], bb[ni], acc[mi][ni], 0, 0, 0);
    }
}

// ------------------------------------------------------------- QKV GEMM
// n in [0,3072): which=n>>10 (uniform per block), h=(n>>6)&15, d=n&63.
// q pre-scaled by 1/8 (softmax scale). q/k/v all stored [b,h,t,d] bf16.
__global__ __launch_bounds__(256) void k_gemm_qkv(
    const bf16* __restrict__ A, const bf16* __restrict__ Bw,
    const float* __restrict__ bias,
    bf16* __restrict__ qb, bf16* __restrict__ kb, bf16* __restrict__ vb) {
    __shared__ bf16 As[128 * 32];
    __shared__ bf16 Bs[128 * 32];
    const int tid = threadIdx.x;
    const int m0 = blockIdx.y * 128, n0 = blockIdx.x * 128;
    f32x4 acc[4][4];
    gemm_core(A, Bw, As, Bs, m0, n0, tid, acc);
    const int lane = tid & 63, wv = tid >> 6;
    const int quad = lane >> 4, lo = lane & 15;
    const int wm = (wv >> 1) * 64, wn = (wv & 1) * 64;
    const int which = n0 >> 10;
    bf16* dst = which == 0 ? qb : (which == 1 ? kb : vb);
    const float scale = which == 0 ? 0.125f : 1.0f;
#pragma unroll
    for (int ni = 0; ni < 4; ++ni) {
        int n = n0 + wn + ni * 16 + lo;
        int h = (n >> 6) & 15, d = n & 63;
        float bv = bias[n];
#pragma unroll
        for (int mi = 0; mi < 4; ++mi) {
#pragma unroll
            for (int r = 0; r < 4; ++r) {
                int m = m0 + wm + mi * 16 + quad * 4 + r;  // C row = quad*4+reg
                int b = m >> 11, t = m & 2047;
                float v = (acc[mi][ni][r] + bv) * scale;
                dst[((size_t)(b * 16 + h) * 2048 + t) * 64 + d] = (bf16)v;
            }
        }
    }
}

// ------------------------------------------------------------ out-proj GEMM
__global__ __launch_bounds__(256) void k_gemm_out(
    const bf16* __restrict__ A, const bf16* __restrict__ Bw,
    const float* __restrict__ bias, float* __restrict__ out) {
    __shared__ bf16 As[128 * 32];
    __shared__ bf16 Bs[128 * 32];
    const int tid = threadIdx.x;
    const int m0 = blockIdx.y * 128, n0 = blockIdx.x * 128;
    f32x4 acc[4][4];
    gemm_core(A, Bw, As, Bs, m0, n0, tid, acc);
    const int lane = tid & 63, wv = tid >> 6;
    const int quad = lane >> 4, lo = lane & 15;
    const int wm = (wv >> 1) * 64, wn = (wv & 1) * 64;
#pragma unroll
    for (int ni = 0; ni < 4; ++ni) {
        int n = n0 + wn + ni * 16 + lo;
        float bv = bias[n];
#pragma unroll
        for (int mi = 0; mi < 4; ++mi) {
#pragma unroll
            for (int r = 0; r < 4; ++r) {
                int m = m0 + wm + mi * 16 + quad * 4 + r;
                out[(size_t)m * 1024 + n] = acc[mi][ni][r] + bv;
            }
        }
    }
}

// ------------------------------------------------------------ V transpose
// per head [2048 t][64 d] -> [64 d][2048 t], 64x64 tiles via padded LDS.
__global__ __launch_bounds__(256) void k_vtrans(
    const bf16* __restrict__ vb, bf16* __restrict__ vt) {
    __shared__ bf16 L[64 * 72];  // pad 72: row stride 144B = 9*16B (aligned, conflict-free-ish)
    const int bh = blockIdx.y, t0 = blockIdx.x * 64;
    const bf16* src = vb + (size_t)bh * 2048 * 64 + (size_t)t0 * 64;
    bf16* dst = vt + (size_t)bh * 64 * 2048 + t0;
    const int tid = threadIdx.x;
#pragma unroll
    for (int p = 0; p < 2; ++p) {
        int idx = p * 256 + tid;       // 512 chunks of 8
        int t = idx >> 3, dc = idx & 7;
        bf16x8 v = *(const bf16x8*)(src + t * 64 + dc * 8);
#pragma unroll
        for (int j = 0; j < 8; ++j) L[(dc * 8 + j) * 72 + t] = v[j];
    }
    __syncthreads();
#pragma unroll
    for (int p = 0; p < 2; ++p) {
        int idx = p * 256 + tid;
        int d = idx >> 3, tc = idx & 7;
        bf16x8 v = *(const bf16x8*)(L + d * 72 + tc * 8);
        *(bf16x8*)(dst + (size_t)d * 2048 + tc * 8) = v;
    }
}

// ---------------------------------------------------------- flash attention
// Q-tile 128 rows (4 waves x 32 rows), key-tile 64. Q pre-scaled by 1/8.
// LDS: Qs 16KB + Ks 8KB + Vs 8KB + Ps 16KB = 48KB.
__global__ __launch_bounds__(256) void k_attn(
    const bf16* __restrict__ qg, const bf16* __restrict__ kg,
    const bf16* __restrict__ vtg, bf16* __restrict__ og) {
    __shared__ bf16 Qs[128 * 64];
    __shared__ bf16 Ks[64 * 64];
    __shared__ bf16 Vs[64 * 64];       // [d][s]
    __shared__ bf16 Ps[4][32 * 64];    // per-wave P, swizzled
    const int tid = threadIdx.x, lane = tid & 63, wv = tid >> 6;
    const int quad = lane >> 4, lo = lane & 15;
    const int bh = blockIdx.y, q0 = blockIdx.x * 128;
    const bf16* Qb = qg + (size_t)bh * 2048 * 64;
    const bf16* Kb = kg + (size_t)bh * 2048 * 64;
    const bf16* Vb = vtg + (size_t)bh * 64 * 2048;
    bf16* Pw = &Ps[wv][0];
    const int wr = wv * 32;

    // stage Q once (8192 elems, 4 passes of 256x16B), chunk-swizzled by row&7
#pragma unroll
    for (int p = 0; p < 4; ++p) {
        int idx = p * 256 + tid;
        int row = idx >> 3, sc = idx & 7;
        int g = sc ^ (row & 7);
        gload16(Qb + (q0 + row) * 64 + g * 8, Qs + p * 2048 + (tid & 192) * 8);
    }

    f32x4 oacc[2][4];
    float mst[2][4], lst[2][4];
#pragma unroll
    for (int mi = 0; mi < 2; ++mi)
#pragma unroll
        for (int ni = 0; ni < 4; ++ni) oacc[mi][ni] = 0.0f;
#pragma unroll
    for (int mi = 0; mi < 2; ++mi)
#pragma unroll
        for (int r = 0; r < 4; ++r) { mst[mi][r] = -1e30f; lst[mi][r] = 0.0f; }

    for (int s0 = 0; s0 < SEQ_T; s0 += 64) {
        __syncthreads();  // all waves done reading Ks/Vs of previous tile
#pragma unroll
        for (int p = 0; p < 2; ++p) {
            int idx = p * 256 + tid;
            int row = idx >> 3, sc = idx & 7;
            int g = sc ^ (row & 7);
            gload16(Kb + (s0 + row) * 64 + g * 8, Ks + p * 2048 + (tid & 192) * 8);
            gload16(Vb + (size_t)row * 2048 + s0 + g * 8, Vs + p * 2048 + (tid & 192) * 8);
        }
        __syncthreads();  // vmcnt drained before barrier (compiler-enforced)

        // S = Q*K^T (already /8 via Q): wave rows [wr, wr+32), cols [0,64)
        f32x4 sacc[2][4];
#pragma unroll
        for (int mi = 0; mi < 2; ++mi)
#pragma unroll
            for (int ni = 0; ni < 4; ++ni) sacc[mi][ni] = 0.0f;
#pragma unroll
        for (int ks = 0; ks < 2; ++ks) {
            bf16x8 aq[2], bk[4];
#pragma unroll
            for (int mi = 0; mi < 2; ++mi) {
                int row = wr + mi * 16 + lo;
                int c = ks * 4 + quad;
                aq[mi] = *(const bf16x8*)(Qs + row * 64 + ((c ^ (row & 7)) * 8));
            }
#pragma unroll
            for (int ni = 0; ni < 4; ++ni) {
                int row = ni * 16 + lo;
                int c = ks * 4 + quad;
                bk[ni] = *(const bf16x8*)(Ks + row * 64 + ((c ^ (row & 7)) * 8));
            }
#pragma unroll
            for (int mi = 0; mi < 2; ++mi)
#pragma unroll
                for (int ni = 0; ni < 4; ++ni)
                    sacc[mi][ni] = __builtin_amdgcn_mfma_f32_16x16x32_bf16(
                        aq[mi], bk[ni], sacc[mi][ni], 0, 0, 0);
        }

        // online softmax: row owned by one quad (16 lanes) -> shfl_xor reduce
#pragma unroll
        for (int mi = 0; mi < 2; ++mi) {
#pragma unroll
            for (int r = 0; r < 4; ++r) {
                float mx = sacc[mi][0][r];
#pragma unroll
                for (int ni = 1; ni < 4; ++ni) mx = fmaxf(mx, sacc[mi][ni][r]);
#pragma unroll
                for (int sh = 1; sh < 16; sh <<= 1) mx = fmaxf(mx, __shfl_xor(mx, sh));
                float mold = mst[mi][r];
                float mnew = fmaxf(mold, mx);
                float alpha = __expf(mold - mnew);
                float rs = 0.0f;
#pragma unroll
                for (int ni = 0; ni < 4; ++ni) {
                    float p = __expf(sacc[mi][ni][r] - mnew);
                    sacc[mi][ni][r] = p;
                    rs += p;
                }
#pragma unroll
                for (int sh = 1; sh < 16; sh <<= 1) rs += __shfl_xor(rs, sh);
                lst[mi][r] = lst[mi][r] * alpha + rs;
                mst[mi][r] = mnew;
#pragma unroll
                for (int ni = 0; ni < 4; ++ni) oacc[mi][ni][r] *= alpha;
                // P: C/D layout -> LDS (A-operand layout), chunk swizzle row&7
                int row = mi * 16 + quad * 4 + r;
#pragma unroll
                for (int ni = 0; ni < 4; ++ni) {
                    int col = ni * 16 + lo;
                    int cc = col >> 3;
                    Pw[row * 64 + ((cc ^ (row & 7)) * 8) + (col & 7)] =
                        (bf16)sacc[mi][ni][r];
                }
            }
        }

        // O += P * V  (Pw per-wave: same-wave write->read, no barrier needed)
#pragma unroll
        for (int ks = 0; ks < 2; ++ks) {
            bf16x8 ap[2], bv8[4];
#pragma unroll
            for (int mi = 0; mi < 2; ++mi) {
                int row = mi * 16 + lo;
                int c = ks * 4 + quad;
                ap[mi] = *(const bf16x8*)(Pw + row * 64 + ((c ^ (row & 7)) * 8));
            }
#pragma unroll
            for (int ni = 0; ni < 4; ++ni) {
                int row = ni * 16 + lo;
                int c = ks * 4 + quad;
                bv8[ni] = *(const bf16x8*)(Vs + row * 64 + ((c ^ (row & 7)) * 8));
            }
#pragma unroll
            for (int mi = 0; mi < 2; ++mi)
#pragma unroll
                for (int ni = 0; ni < 4; ++ni)
                    oacc[mi][ni] = __builtin_amdgcn_mfma_f32_16x16x32_bf16(
                        ap[mi], bv8[ni], oacc[mi][ni], 0, 0, 0);
        }
    }

    // epilogue: O/l -> attn_out [b, t, h*64+d] bf16
    const int b = bh >> 4, h = bh & 15;
#pragma unroll
    for (int mi = 0; mi < 2; ++mi) {
#pragma unroll
        for (int r = 0; r < 4; ++r) {
            float inv = 1.0f / lst[mi][r];
            int trow = q0 + wr + mi * 16 + quad * 4 + r;
#pragma unroll
            for (int ni = 0; ni < 4; ++ni) {
                og[((size_t)b * 2048 + trow) * 1024 + h * 64 + ni * 16 + lo] =
                    (bf16)(oacc[mi][ni][r] * inv);
            }
        }
    }
}

// ---------------------------------------------------------------- launcher
extern "C" void kernel_launch(void* const* d_in, const int* in_sizes, int n_in,
                              void* d_out, int out_size, void* d_ws, size_t ws_size,
                              hipStream_t stream) {
    const float* x     = (const float*)d_in[0];
    const float* qkv_w = (const float*)d_in[1];
    const float* qkv_b = (const float*)d_in[2];
    const float* out_w = (const float*)d_in[3];
    const float* out_b = (const float*)d_in[4];
    float* out = (float*)d_out;
    char* ws = (char*)d_ws;
    // ws layout (48 MB total)
    bf16* xb  = (bf16*)(ws);                       // 8 MB  [4096][1024]
    bf16* wqb = (bf16*)(ws + 8388608);             // 6 MB  [3072][1024]
    bf16* wob = (bf16*)(ws + 14680064);            // 2 MB  [1024][1024]
    bf16* qb  = (bf16*)(ws + 16777216);            // 8 MB  [b,h,t,d]
    bf16* kb  = (bf16*)(ws + 25165824);            // 8 MB  [b,h,t,d]
    bf16* vb  = (bf16*)(ws + 33554432);            // 8 MB  [b,h,t,d]
    bf16* ao  = (bf16*)(ws + 41943040);            // 8 MB  [4096][1024]
    bf16* vt  = xb;  // alias: xb dead after QKV GEMM; vt = [b,h,d,t]

    k_convert<<<8192, 256, 0, stream>>>(x, qkv_w, out_w, xb, wqb, wob);
    k_gemm_qkv<<<dim3(24, 32), 256, 0, stream>>>(xb, wqb, qkv_b, qb, kb, vb);
    k_vtrans<<<dim3(32, 32), 256, 0, stream>>>(vb, vt);
    k_attn<<<dim3(16, 32), 256, 0, stream>>>(qb, kb, vt, ao);
    k_gemm_out<<<dim3(8, 32), 256, 0, stream>>>(ao, wob, out_b, out);
}